// Round 7
// baseline (9322.708 us; speedup 1.0000x reference)
//
#include <hip/hip_runtime.h>

// VectorQuantizer: z [8,4096,256] f32, E [8192,256] f32.
// numpy-fp32 semantics: dist[n,k] = fl(fl(A[n]-2*dot32[n,k])+C[k]), argmin first-index,
// dot32 = SSE sum-of-products (4 mod-4 lane accs, unfused, (s0+s1)+(s2+s3)).
// p1: bf16 MFMA GEMM -> candidate superset {k : t~ <= min(t~) + 16 ulp(A)}.
// p2: exact SSE rescore, ONE LANE per candidate (4 static accumulators), u64 lex-min.
// pfull: parallel block-scan for overflow rows (replaces round-5's 3ms single-wave crawl).

#define KCODES 8192
#define DIM    256
#define NROWS  32768
#define BM     128
#define KT     256
#define CAPL   32
#define CAPG   16

typedef __attribute__((ext_vector_type(8))) short short8_t; // 8 bf16
typedef __attribute__((ext_vector_type(4))) float f32x4_t;

__device__ __forceinline__ unsigned cvt_pk_bf16(float lo, float hi)
{
    unsigned r;
    asm("v_cvt_pk_bf16_f32 %0, %1, %2" : "=v"(r) : "v"(lo), "v"(hi));
    return r;
}

// ---- exact numpy pairwise fp32 sum of squares (bit-exact, proven r2/r4/r5) ----
__device__ __forceinline__ float np_sumsq_256(const float* __restrict__ x)
{
    float blk[2];
#pragma unroll
    for (int b = 0; b < 2; ++b) {
        const float* p = x + 128 * b;
        float r[8];
        float4 v0 = *reinterpret_cast<const float4*>(p);
        float4 v1 = *reinterpret_cast<const float4*>(p + 4);
        r[0] = __fmul_rn(v0.x, v0.x); r[1] = __fmul_rn(v0.y, v0.y);
        r[2] = __fmul_rn(v0.z, v0.z); r[3] = __fmul_rn(v0.w, v0.w);
        r[4] = __fmul_rn(v1.x, v1.x); r[5] = __fmul_rn(v1.y, v1.y);
        r[6] = __fmul_rn(v1.z, v1.z); r[7] = __fmul_rn(v1.w, v1.w);
        for (int i = 8; i < 128; i += 8) {
            float4 w0 = *reinterpret_cast<const float4*>(p + i);
            float4 w1 = *reinterpret_cast<const float4*>(p + i + 4);
            r[0] = __fadd_rn(r[0], __fmul_rn(w0.x, w0.x));
            r[1] = __fadd_rn(r[1], __fmul_rn(w0.y, w0.y));
            r[2] = __fadd_rn(r[2], __fmul_rn(w0.z, w0.z));
            r[3] = __fadd_rn(r[3], __fmul_rn(w0.w, w0.w));
            r[4] = __fadd_rn(r[4], __fmul_rn(w1.x, w1.x));
            r[5] = __fadd_rn(r[5], __fmul_rn(w1.y, w1.y));
            r[6] = __fadd_rn(r[6], __fmul_rn(w1.z, w1.z));
            r[7] = __fadd_rn(r[7], __fmul_rn(w1.w, w1.w));
        }
        blk[b] = __fadd_rn(__fadd_rn(__fadd_rn(r[0], r[1]), __fadd_rn(r[2], r[3])),
                           __fadd_rn(__fadd_rn(r[4], r[5]), __fadd_rn(r[6], r[7])));
    }
    return __fadd_rn(blk[0], blk[1]);
}

__global__ void vq_rowsq(const float* __restrict__ X, float* __restrict__ out, int nrows)
{
    const int r = blockIdx.x * blockDim.x + threadIdx.x;
    if (r < nrows) out[r] = np_sumsq_256(X + (size_t)r * DIM);
}

// ---- phase 1: bf16 MFMA GEMM + running-min + candidate collection (8 waves) ----
__global__ __launch_bounds__(512, 2)
void vq_p1(const float* __restrict__ z, const float* __restrict__ E,
           const float* __restrict__ A32, const float* __restrict__ C32,
           int* __restrict__ counts, unsigned short* __restrict__ candg)
{
    __shared__ unsigned short zsh[BM * 256];     // 64KB, 16B-slot swz: slot^(row&7)
    __shared__ unsigned short esh[KT * 64];      // 32KB, per 64-d chunk
    __shared__ float cbuf[KT];                   // 1KB
    __shared__ float scandT[BM * CAPL];          // 16KB
    __shared__ unsigned short scandK[BM * CAPL]; // 8KB
    __shared__ int scnt[BM];
    __shared__ float rthr[4][BM];

    const int tid  = threadIdx.x;
    const int lane = tid & 63;
    const int wave = tid >> 6;          // 0..7
    const int wr = wave >> 2;           // rows 64*wr ..
    const int wc = wave & 3;            // codes 64*wc ..
    const int l15 = lane & 15, l4 = lane >> 4;
    const int rowBase = blockIdx.x * BM;

    // stage z once: row = tid>>2, 64-d quarter = tid&3
    {
        const int r = tid >> 2, hf = tid & 3;
        const float* zp = z + (size_t)(rowBase + r) * DIM + hf * 64;
#pragma unroll
        for (int i = 0; i < 16; ++i) {
            float4 v = reinterpret_cast<const float4*>(zp)[i];
            unsigned lo = cvt_pk_bf16(v.x, v.y), hi = cvt_pk_bf16(v.z, v.w);
            const int slot = hf * 8 + (i >> 1);
            const int sub  = (i & 1) * 4;
            *reinterpret_cast<uint2*>(&zsh[r * 256 + ((slot ^ (r & 7)) << 3) + sub]) =
                make_uint2(lo, hi);
        }
    }
    if (tid < BM) scnt[tid] = 0;

    float runm[16], Wv[16];
#pragma unroll
    for (int rf = 0; rf < 4; ++rf)
#pragma unroll
        for (int reg = 0; reg < 4; ++reg) {
            const float a = A32[rowBase + 64 * wr + 16 * rf + 4 * l4 + reg];
            const unsigned ebits = (__float_as_uint(a) >> 23) & 255u;
            Wv[rf * 4 + reg] = __uint_as_float((ebits - 19u) << 23);  // 16 ulp(A)
            runm[rf * 4 + reg] = 1e30f;
        }
    __syncthreads();

#pragma unroll 1
    for (int kt = 0; kt < KCODES; kt += KT) {
        f32x4_t acc[4][4];
#pragma unroll
        for (int rf = 0; rf < 4; ++rf)
#pragma unroll
            for (int cf = 0; cf < 4; ++cf) acc[rf][cf] = (f32x4_t){0.f, 0.f, 0.f, 0.f};

#pragma unroll 1
        for (int c = 0; c < 4; ++c) {
            __syncthreads();
            if (c == 0 && tid < KT) cbuf[tid] = C32[kt + tid];
            // stage E chunk [256 codes][64 d]
#pragma unroll
            for (int i = 0; i < 8; ++i) {
                const int gi = i * 512 + tid;
                const int code = gi >> 4, dp = gi & 15;
                float4 v = *reinterpret_cast<const float4*>(
                    &E[(size_t)(kt + code) * DIM + c * 64 + dp * 4]);
                unsigned lo = cvt_pk_bf16(v.x, v.y), hi = cvt_pk_bf16(v.z, v.w);
                const int slot = dp >> 1, sub = (dp & 1) * 4;
                *reinterpret_cast<uint2*>(
                    &esh[code * 64 + ((slot ^ (code & 7)) << 3) + sub]) = make_uint2(lo, hi);
            }
            __syncthreads();
#pragma unroll
            for (int ks = 0; ks < 2; ++ks) {
                short8_t a[4], b[4];
#pragma unroll
                for (int rf = 0; rf < 4; ++rf) {
                    const int row = 64 * wr + 16 * rf + l15;
                    const int slot = 8 * c + 4 * ks + l4;
                    a[rf] = *reinterpret_cast<const short8_t*>(
                        &zsh[row * 256 + ((slot ^ (row & 7)) << 3)]);
                }
#pragma unroll
                for (int cf = 0; cf < 4; ++cf) {
                    const int code = 64 * wc + 16 * cf + l15;
                    const int slot = 4 * ks + l4;
                    b[cf] = *reinterpret_cast<const short8_t*>(
                        &esh[code * 64 + ((slot ^ (code & 7)) << 3)]);
                }
#pragma unroll
                for (int rf = 0; rf < 4; ++rf)
#pragma unroll
                    for (int cf = 0; cf < 4; ++cf)
                        acc[rf][cf] = __builtin_amdgcn_mfma_f32_16x16x32_bf16(
                            a[rf], b[cf], acc[rf][cf], 0, 0, 0);
            }
        }

        // epilogue: t = C - 2*dot; row-min over 16 l15-lanes x 4 cf; append
#pragma unroll
        for (int rf = 0; rf < 4; ++rf) {
#pragma unroll
            for (int reg = 0; reg < 4; ++reg) {
                float t[4];
#pragma unroll
                for (int cf = 0; cf < 4; ++cf)
                    t[cf] = fmaf(-2.0f, acc[rf][cf][reg], cbuf[64 * wc + 16 * cf + l15]);
                float m = fminf(fminf(t[0], t[1]), fminf(t[2], t[3]));
                m = fminf(m, __shfl_xor(m, 1));
                m = fminf(m, __shfl_xor(m, 2));
                m = fminf(m, __shfl_xor(m, 4));
                m = fminf(m, __shfl_xor(m, 8));
                const int idx = rf * 4 + reg;
                runm[idx] = fminf(runm[idx], m);
                const float thr = runm[idx] + Wv[idx];
                const int rl = 64 * wr + 16 * rf + 4 * l4 + reg;
#pragma unroll
                for (int cf = 0; cf < 4; ++cf) {
                    if (t[cf] <= thr) {
                        const int ai = atomicAdd(&scnt[rl], 1);
                        if (ai < CAPL) {
                            scandT[rl * CAPL + ai] = t[cf];
                            scandK[rl * CAPL + ai] =
                                (unsigned short)(kt + 64 * wc + 16 * cf + l15);
                        }
                    }
                }
            }
        }
    }

    if (l15 == 0) {
#pragma unroll
        for (int rf = 0; rf < 4; ++rf)
#pragma unroll
            for (int reg = 0; reg < 4; ++reg)
                rthr[wc][64 * wr + 16 * rf + 4 * l4 + reg] =
                    runm[rf * 4 + reg] + Wv[rf * 4 + reg];
    }
    __syncthreads();
    if (tid < BM) {
        const int row = rowBase + tid;
        const float thrF = fminf(fminf(rthr[0][tid], rthr[1][tid]),
                                 fminf(rthr[2][tid], rthr[3][tid]));
        const int n = scnt[tid];
        if (n > CAPL) { counts[row] = -1; }
        else {
            int m = 0;
            for (int i = 0; i < n; ++i) {
                if (scandT[tid * CAPL + i] <= thrF) {
                    if (m < CAPG) candg[(size_t)row * CAPG + m] = scandK[tid * CAPL + i];
                    ++m;
                }
            }
            counts[row] = (m <= CAPG) ? m : -1;
        }
    }
}

// ---- phase 2: exact SSE rescore, one LANE per candidate, u64 lex-min ----
__global__ __launch_bounds__(256)
void vq_p2(const float* __restrict__ z, const float* __restrict__ E,
           const float* __restrict__ A32, const float* __restrict__ C32,
           const int* __restrict__ counts, const unsigned short* __restrict__ candg,
           int* __restrict__ widx)
{
    __shared__ float zsh[4][256];
    const int lane = threadIdx.x & 63;
    const int w = threadIdx.x >> 6;
    const int row = blockIdx.x * 4 + w;
    const int cnt = counts[row];
    if (cnt == 1) {   // sole member of the provable superset IS the np argmin
        if (lane == 0) widx[row] = (int)candg[(size_t)row * CAPG];
        return;
    }
    if (cnt <= 0 || cnt > CAPG) return;   // handled by vq_pfull
    {
        float4 v = *reinterpret_cast<const float4*>(&z[(size_t)row * DIM + lane * 4]);
        *reinterpret_cast<float4*>(&zsh[w][lane * 4]) = v;
    }
    asm volatile("s_waitcnt lgkmcnt(0)" ::: "memory");
    __builtin_amdgcn_sched_barrier(0);
    const int cl = lane < cnt ? lane : cnt - 1;
    const int myk = (int)candg[(size_t)row * CAPG + cl];
    const float* er = E + (size_t)myk * DIM;
    // SSE emulation in-lane: 4 static accumulators over float4 components
    float s0 = 0.f, s1 = 0.f, s2 = 0.f, s3 = 0.f;
#pragma unroll 16
    for (int t = 0; t < 64; ++t) {
        const float4 ev = *reinterpret_cast<const float4*>(er + 4 * t);
        const float4 zv = *reinterpret_cast<const float4*>(&zsh[w][4 * t]);
        s0 = __fadd_rn(s0, __fmul_rn(zv.x, ev.x));
        s1 = __fadd_rn(s1, __fmul_rn(zv.y, ev.y));
        s2 = __fadd_rn(s2, __fmul_rn(zv.z, ev.z));
        s3 = __fadd_rn(s3, __fmul_rn(zv.w, ev.w));
    }
    const float dot = __fadd_rn(__fadd_rn(s0, s1), __fadd_rn(s2, s3));
    const float dist = __fadd_rn(__fsub_rn(A32[row], 2.0f * dot), C32[myk]);
    unsigned long long key =
        ((unsigned long long)__float_as_uint(dist) << 13) | (unsigned)myk;
    if (lane >= cnt) key = ~0ull;
#pragma unroll
    for (int off = 1; off < 64; off <<= 1) {
        const unsigned long long ok = __shfl_xor(key, off);
        key = ok < key ? ok : key;
    }
    if (lane == 0) widx[row] = (int)(key & (KCODES - 1));
}

// ---- parallel full-scan for overflow rows (rare); whole block per row ----
__global__ __launch_bounds__(256)
void vq_pfull(const float* __restrict__ z, const float* __restrict__ E,
              const float* __restrict__ A32, const float* __restrict__ C32,
              const int* __restrict__ counts, int* __restrict__ widx)
{
    __shared__ float zsh[256];
    __shared__ unsigned long long skey;
    __shared__ int rlist[BM];
    __shared__ int rcnt;
    const int tid = threadIdx.x;
    if (tid == 0) rcnt = 0;
    __syncthreads();
    if (tid < BM) {
        const int row = blockIdx.x * BM + tid;
        const int c = counts[row];
        if (c <= 0 || c > CAPG) rlist[atomicAdd(&rcnt, 1)] = row;
    }
    __syncthreads();
    const int nbad = rcnt;
    for (int it = 0; it < nbad; ++it) {
        const int row = rlist[it];
        if (tid == 0) skey = ~0ull;
        if (tid < 64) {
            float4 v = *reinterpret_cast<const float4*>(&z[(size_t)row * DIM + tid * 4]);
            *reinterpret_cast<float4*>(&zsh[tid * 4]) = v;
        }
        __syncthreads();
        const float Ar = A32[row];
        unsigned long long best = ~0ull;
        for (int i = 0; i < KCODES / 256; ++i) {
            const int k = i * 256 + tid;
            const float* er = E + (size_t)k * DIM;
            float s0 = 0.f, s1 = 0.f, s2 = 0.f, s3 = 0.f;
#pragma unroll 16
            for (int t = 0; t < 64; ++t) {
                const float4 ev = *reinterpret_cast<const float4*>(er + 4 * t);
                const float4 zv = *reinterpret_cast<const float4*>(&zsh[4 * t]);
                s0 = __fadd_rn(s0, __fmul_rn(zv.x, ev.x));
                s1 = __fadd_rn(s1, __fmul_rn(zv.y, ev.y));
                s2 = __fadd_rn(s2, __fmul_rn(zv.z, ev.z));
                s3 = __fadd_rn(s3, __fmul_rn(zv.w, ev.w));
            }
            const float dot = __fadd_rn(__fadd_rn(s0, s1), __fadd_rn(s2, s3));
            const float dist = __fadd_rn(__fsub_rn(Ar, 2.0f * dot), C32[k]);
            const unsigned long long key =
                ((unsigned long long)__float_as_uint(dist) << 13) | (unsigned)k;
            best = key < best ? key : best;
        }
        atomicMin(&skey, best);
        __syncthreads();
        if (tid == 0) widx[row] = (int)(skey & (KCODES - 1));
        __syncthreads();
    }
}

__global__ void vq_gather(const float* __restrict__ E, const int* __restrict__ widx,
                          float* __restrict__ out)
{
    const int gid = blockIdx.x * 256 + threadIdx.x;
    const int n  = gid >> 6;
    const int d4 = gid & 63;
    const int k = widx[n] & (KCODES - 1);   // clamp: safety against unwritten slot
    reinterpret_cast<float4*>(out)[(size_t)n * 64 + d4] =
        reinterpret_cast<const float4*>(E)[(size_t)k * 64 + d4];
}

extern "C" void kernel_launch(void* const* d_in, const int* in_sizes, int n_in,
                              void* d_out, int out_size, void* d_ws, size_t ws_size,
                              hipStream_t stream)
{
    const float* zp = (const float*)d_in[0];
    const float* Ep = (const float*)d_in[1];
    float* out = (float*)d_out;
    char* ws = (char*)d_ws;

    float* A32    = (float*)ws;                              // 131072 B
    float* C32    = (float*)(ws + 131072);                   //  32768 B
    int*   widx   = (int*)(ws + 163840);                     // 131072 B
    int*   counts = (int*)(ws + 294912);                     // 131072 B
    unsigned short* candg = (unsigned short*)(ws + 425984);  // 32768*16*2 = 1 MB

    vq_rowsq<<<NROWS / 256, 256, 0, stream>>>(zp, A32, NROWS);
    vq_rowsq<<<KCODES / 256, 256, 0, stream>>>(Ep, C32, KCODES);
    vq_p1<<<NROWS / BM, 512, 0, stream>>>(zp, Ep, A32, C32, counts, candg);
    vq_p2<<<NROWS / 4, 256, 0, stream>>>(zp, Ep, A32, C32, counts, candg, widx);
    vq_pfull<<<NROWS / BM, 256, 0, stream>>>(zp, Ep, A32, C32, counts, widx);
    vq_gather<<<NROWS * (DIM / 4) / 256, 256, 0, stream>>>(Ep, widx, out);
}

// Round 8
// 528.231 us; speedup vs baseline: 17.6489x; 17.6489x over previous
//
#include <hip/hip_runtime.h>

// VectorQuantizer: z [8,4096,256] f32, E [8192,256] f32.
// numpy-fp32 semantics: dist[n,k] = fl(fl(A[n]-2*dot32[n,k])+C[k]), argmin first-index,
// dot32 = SSE sum-of-products (4 mod-4 lane accs, unfused, (s0+s1)+(s2+s3)).
// p1: bf16 MFMA GEMM -> candidate superset {k : t~ <= globalmin(t~) + 16 ulp(A)},
//     with CROSS-PARTITION shared running min (LDS atomicMin) to kill append inflation.
// p2: exact SSE rescore, one lane per candidate, u64 lex-min = np first-index argmin.
// pfull: grid-stride parallel full scan over compacted bad-row list (load-balanced).

#define KCODES 8192
#define DIM    256
#define NROWS  32768
#define BM     128
#define KT     256
#define CAPL   64
#define CAPG   16

typedef __attribute__((ext_vector_type(8))) short short8_t; // 8 bf16
typedef __attribute__((ext_vector_type(4))) float f32x4_t;

__device__ __forceinline__ unsigned cvt_pk_bf16(float lo, float hi)
{
    unsigned r;
    asm("v_cvt_pk_bf16_f32 %0, %1, %2" : "=v"(r) : "v"(lo), "v"(hi));
    return r;
}

// monotone float<->uint map (valid for all non-NaN floats)
__device__ __forceinline__ unsigned fmap(float f)
{
    unsigned u = __float_as_uint(f);
    return (u & 0x80000000u) ? ~u : (u | 0x80000000u);
}
__device__ __forceinline__ float funmap(unsigned m)
{
    unsigned u = (m & 0x80000000u) ? (m & 0x7fffffffu) : ~m;
    return __uint_as_float(u);
}

// ---- exact numpy pairwise fp32 sum of squares (bit-exact, proven r2-r7) ----
__device__ __forceinline__ float np_sumsq_256(const float* __restrict__ x)
{
    float blk[2];
#pragma unroll
    for (int b = 0; b < 2; ++b) {
        const float* p = x + 128 * b;
        float r[8];
        float4 v0 = *reinterpret_cast<const float4*>(p);
        float4 v1 = *reinterpret_cast<const float4*>(p + 4);
        r[0] = __fmul_rn(v0.x, v0.x); r[1] = __fmul_rn(v0.y, v0.y);
        r[2] = __fmul_rn(v0.z, v0.z); r[3] = __fmul_rn(v0.w, v0.w);
        r[4] = __fmul_rn(v1.x, v1.x); r[5] = __fmul_rn(v1.y, v1.y);
        r[6] = __fmul_rn(v1.z, v1.z); r[7] = __fmul_rn(v1.w, v1.w);
        for (int i = 8; i < 128; i += 8) {
            float4 w0 = *reinterpret_cast<const float4*>(p + i);
            float4 w1 = *reinterpret_cast<const float4*>(p + i + 4);
            r[0] = __fadd_rn(r[0], __fmul_rn(w0.x, w0.x));
            r[1] = __fadd_rn(r[1], __fmul_rn(w0.y, w0.y));
            r[2] = __fadd_rn(r[2], __fmul_rn(w0.z, w0.z));
            r[3] = __fadd_rn(r[3], __fmul_rn(w0.w, w0.w));
            r[4] = __fadd_rn(r[4], __fmul_rn(w1.x, w1.x));
            r[5] = __fadd_rn(r[5], __fmul_rn(w1.y, w1.y));
            r[6] = __fadd_rn(r[6], __fmul_rn(w1.z, w1.z));
            r[7] = __fadd_rn(r[7], __fmul_rn(w1.w, w1.w));
        }
        blk[b] = __fadd_rn(__fadd_rn(__fadd_rn(r[0], r[1]), __fadd_rn(r[2], r[3])),
                           __fadd_rn(__fadd_rn(r[4], r[5]), __fadd_rn(r[6], r[7])));
    }
    return __fadd_rn(blk[0], blk[1]);
}

__global__ void vq_rowsq(const float* __restrict__ X, float* __restrict__ out, int nrows)
{
    const int r = blockIdx.x * blockDim.x + threadIdx.x;
    if (r < nrows) out[r] = np_sumsq_256(X + (size_t)r * DIM);
}

// ---- phase 1: bf16 MFMA GEMM + shared running-min + candidate collection ----
__global__ __launch_bounds__(512, 2)
void vq_p1(const float* __restrict__ z, const float* __restrict__ E,
           const float* __restrict__ A32, const float* __restrict__ C32,
           int* __restrict__ counts, unsigned short* __restrict__ candg,
           int* __restrict__ badcnt, int* __restrict__ badlist)
{
    __shared__ unsigned short zsh[BM * 256];     // 64KB, 16B-slot swz: slot^(row&7)
    __shared__ unsigned short esh[KT * 64];      // 32KB, per 64-d chunk
    __shared__ float cbuf[KT];                   // 1KB
    __shared__ float scandT[BM * CAPL];          // 32KB
    __shared__ unsigned short scandK[BM * CAPL]; // 16KB
    __shared__ int scnt[BM];                     // 0.5KB
    __shared__ unsigned rminu[BM];               // 0.5KB  shared global row min

    const int tid  = threadIdx.x;
    const int lane = tid & 63;
    const int wave = tid >> 6;          // 0..7
    const int wr = wave >> 2;           // rows 64*wr ..
    const int wc = wave & 3;            // codes 64*wc ..
    const int l15 = lane & 15, l4 = lane >> 4;
    const int rowBase = blockIdx.x * BM;

    // stage z once: row = tid>>2, 64-d quarter = tid&3
    {
        const int r = tid >> 2, hf = tid & 3;
        const float* zp = z + (size_t)(rowBase + r) * DIM + hf * 64;
#pragma unroll
        for (int i = 0; i < 16; ++i) {
            float4 v = reinterpret_cast<const float4*>(zp)[i];
            unsigned lo = cvt_pk_bf16(v.x, v.y), hi = cvt_pk_bf16(v.z, v.w);
            const int slot = hf * 8 + (i >> 1);
            const int sub  = (i & 1) * 4;
            *reinterpret_cast<uint2*>(&zsh[r * 256 + ((slot ^ (r & 7)) << 3) + sub]) =
                make_uint2(lo, hi);
        }
    }
    if (tid < BM) { scnt[tid] = 0; rminu[tid] = 0xFFFFFFFFu; }

    float runm[16], Wv[16];
#pragma unroll
    for (int rf = 0; rf < 4; ++rf)
#pragma unroll
        for (int reg = 0; reg < 4; ++reg) {
            const float a = A32[rowBase + 64 * wr + 16 * rf + 4 * l4 + reg];
            const unsigned ebits = (__float_as_uint(a) >> 23) & 255u;
            Wv[rf * 4 + reg] = __uint_as_float((ebits - 19u) << 23);  // 16 ulp(A)
            runm[rf * 4 + reg] = 1e30f;
        }
    __syncthreads();

#pragma unroll 1
    for (int kt = 0; kt < KCODES; kt += KT) {
        f32x4_t acc[4][4];
#pragma unroll
        for (int rf = 0; rf < 4; ++rf)
#pragma unroll
            for (int cf = 0; cf < 4; ++cf) acc[rf][cf] = (f32x4_t){0.f, 0.f, 0.f, 0.f};

#pragma unroll 1
        for (int c = 0; c < 4; ++c) {
            __syncthreads();
            if (c == 0 && tid < KT) cbuf[tid] = C32[kt + tid];
            // stage E chunk [256 codes][64 d]
#pragma unroll
            for (int i = 0; i < 8; ++i) {
                const int gi = i * 512 + tid;
                const int code = gi >> 4, dp = gi & 15;
                float4 v = *reinterpret_cast<const float4*>(
                    &E[(size_t)(kt + code) * DIM + c * 64 + dp * 4]);
                unsigned lo = cvt_pk_bf16(v.x, v.y), hi = cvt_pk_bf16(v.z, v.w);
                const int slot = dp >> 1, sub = (dp & 1) * 4;
                *reinterpret_cast<uint2*>(
                    &esh[code * 64 + ((slot ^ (code & 7)) << 3) + sub]) = make_uint2(lo, hi);
            }
            __syncthreads();
#pragma unroll
            for (int ks = 0; ks < 2; ++ks) {
                short8_t a[4], b[4];
#pragma unroll
                for (int rf = 0; rf < 4; ++rf) {
                    const int row = 64 * wr + 16 * rf + l15;
                    const int slot = 8 * c + 4 * ks + l4;
                    a[rf] = *reinterpret_cast<const short8_t*>(
                        &zsh[row * 256 + ((slot ^ (row & 7)) << 3)]);
                }
#pragma unroll
                for (int cf = 0; cf < 4; ++cf) {
                    const int code = 64 * wc + 16 * cf + l15;
                    const int slot = 4 * ks + l4;
                    b[cf] = *reinterpret_cast<const short8_t*>(
                        &esh[code * 64 + ((slot ^ (code & 7)) << 3)]);
                }
#pragma unroll
                for (int rf = 0; rf < 4; ++rf)
#pragma unroll
                    for (int cf = 0; cf < 4; ++cf)
                        acc[rf][cf] = __builtin_amdgcn_mfma_f32_16x16x32_bf16(
                            a[rf], b[cf], acc[rf][cf], 0, 0, 0);
            }
        }

        // epilogue: t = C - 2*dot; shared-min tightening; append
#pragma unroll
        for (int rf = 0; rf < 4; ++rf) {
#pragma unroll
            for (int reg = 0; reg < 4; ++reg) {
                float t[4];
#pragma unroll
                for (int cf = 0; cf < 4; ++cf)
                    t[cf] = fmaf(-2.0f, acc[rf][cf][reg], cbuf[64 * wc + 16 * cf + l15]);
                float m = fminf(fminf(t[0], t[1]), fminf(t[2], t[3]));
                m = fminf(m, __shfl_xor(m, 1));
                m = fminf(m, __shfl_xor(m, 2));
                m = fminf(m, __shfl_xor(m, 4));
                m = fminf(m, __shfl_xor(m, 8));
                const int idx = rf * 4 + reg;
                const int rl = 64 * wr + 16 * rf + 4 * l4 + reg;
                float rm = fminf(runm[idx], m);
                if (l15 == 0) atomicMin(&rminu[rl], fmap(rm));
                rm = fminf(rm, funmap(rminu[rl]));   // pull other partitions' min
                runm[idx] = rm;
                const float thr = rm + Wv[idx];
#pragma unroll
                for (int cf = 0; cf < 4; ++cf) {
                    if (t[cf] <= thr) {
                        const int ai = atomicAdd(&scnt[rl], 1);
                        if (ai < CAPL) {
                            scandT[rl * CAPL + ai] = t[cf];
                            scandK[rl * CAPL + ai] =
                                (unsigned short)(kt + 64 * wc + 16 * cf + l15);
                        }
                    }
                }
            }
        }
    }

    __syncthreads();
    if (tid < BM) {
        const int row = rowBase + tid;
        const float a = A32[row];
        const unsigned ebits = (__float_as_uint(a) >> 23) & 255u;
        const float Wr = __uint_as_float((ebits - 19u) << 23);
        const float thrF = funmap(rminu[tid]) + Wr;   // settled global min + W
        const int n = scnt[tid];
        bool bad = (n > CAPL);
        int m = 0;
        if (!bad) {
            for (int i = 0; i < n; ++i) {
                if (scandT[tid * CAPL + i] <= thrF) {
                    if (m < CAPG) candg[(size_t)row * CAPG + m] = scandK[tid * CAPL + i];
                    ++m;
                }
            }
            bad = (m > CAPG);
        }
        counts[row] = bad ? -1 : m;
        if (bad) badlist[atomicAdd(badcnt, 1)] = row;
    }
}

// ---- phase 2: exact SSE rescore, one LANE per candidate, u64 lex-min ----
__global__ __launch_bounds__(256)
void vq_p2(const float* __restrict__ z, const float* __restrict__ E,
           const float* __restrict__ A32, const float* __restrict__ C32,
           const int* __restrict__ counts, const unsigned short* __restrict__ candg,
           int* __restrict__ widx)
{
    __shared__ float zsh[4][256];
    const int lane = threadIdx.x & 63;
    const int w = threadIdx.x >> 6;
    const int row = blockIdx.x * 4 + w;
    const int cnt = counts[row];
    if (cnt == 1) {   // sole member of the provable superset IS the np argmin
        if (lane == 0) widx[row] = (int)candg[(size_t)row * CAPG];
        return;
    }
    if (cnt <= 0 || cnt > CAPG) return;   // handled by vq_pfull
    {
        float4 v = *reinterpret_cast<const float4*>(&z[(size_t)row * DIM + lane * 4]);
        *reinterpret_cast<float4*>(&zsh[w][lane * 4]) = v;
    }
    asm volatile("s_waitcnt lgkmcnt(0)" ::: "memory");
    __builtin_amdgcn_sched_barrier(0);
    const int cl = lane < cnt ? lane : cnt - 1;
    const int myk = (int)candg[(size_t)row * CAPG + cl];
    const float* er = E + (size_t)myk * DIM;
    float s0 = 0.f, s1 = 0.f, s2 = 0.f, s3 = 0.f;
#pragma unroll 16
    for (int t = 0; t < 64; ++t) {
        const float4 ev = *reinterpret_cast<const float4*>(er + 4 * t);
        const float4 zv = *reinterpret_cast<const float4*>(&zsh[w][4 * t]);
        s0 = __fadd_rn(s0, __fmul_rn(zv.x, ev.x));
        s1 = __fadd_rn(s1, __fmul_rn(zv.y, ev.y));
        s2 = __fadd_rn(s2, __fmul_rn(zv.z, ev.z));
        s3 = __fadd_rn(s3, __fmul_rn(zv.w, ev.w));
    }
    const float dot = __fadd_rn(__fadd_rn(s0, s1), __fadd_rn(s2, s3));
    const float dist = __fadd_rn(__fsub_rn(A32[row], 2.0f * dot), C32[myk]);
    unsigned long long key =
        ((unsigned long long)__float_as_uint(dist) << 13) | (unsigned)myk;
    if (lane >= cnt) key = ~0ull;
#pragma unroll
    for (int off = 1; off < 64; off <<= 1) {
        const unsigned long long ok = __shfl_xor(key, off);
        key = ok < key ? ok : key;
    }
    if (lane == 0) widx[row] = (int)(key & (KCODES - 1));
}

// ---- parallel full-scan over compacted bad-row list (grid-stride) ----
__global__ __launch_bounds__(1024)
void vq_pfull(const float* __restrict__ z, const float* __restrict__ E,
              const float* __restrict__ A32, const float* __restrict__ C32,
              const int* __restrict__ badcnt, const int* __restrict__ badlist,
              int* __restrict__ widx)
{
    __shared__ float zsh[256];
    __shared__ unsigned long long skey;
    const int tid = threadIdx.x;
    const int nbad = *badcnt;
    for (int it = blockIdx.x; it < nbad; it += gridDim.x) {
        const int row = badlist[it];
        if (tid == 0) skey = ~0ull;
        if (tid < 64) {
            float4 v = *reinterpret_cast<const float4*>(&z[(size_t)row * DIM + tid * 4]);
            *reinterpret_cast<float4*>(&zsh[tid * 4]) = v;
        }
        __syncthreads();
        const float Ar = A32[row];
        unsigned long long best = ~0ull;
#pragma unroll 1
        for (int i = 0; i < KCODES / 1024; ++i) {
            const int k = i * 1024 + tid;
            const float* er = E + (size_t)k * DIM;
            float s0 = 0.f, s1 = 0.f, s2 = 0.f, s3 = 0.f;
#pragma unroll 16
            for (int t = 0; t < 64; ++t) {
                const float4 ev = *reinterpret_cast<const float4*>(er + 4 * t);
                const float4 zv = *reinterpret_cast<const float4*>(&zsh[4 * t]);
                s0 = __fadd_rn(s0, __fmul_rn(zv.x, ev.x));
                s1 = __fadd_rn(s1, __fmul_rn(zv.y, ev.y));
                s2 = __fadd_rn(s2, __fmul_rn(zv.z, ev.z));
                s3 = __fadd_rn(s3, __fmul_rn(zv.w, ev.w));
            }
            const float dot = __fadd_rn(__fadd_rn(s0, s1), __fadd_rn(s2, s3));
            const float dist = __fadd_rn(__fsub_rn(Ar, 2.0f * dot), C32[k]);
            const unsigned long long key =
                ((unsigned long long)__float_as_uint(dist) << 13) | (unsigned)k;
            best = key < best ? key : best;
        }
#pragma unroll
        for (int off = 1; off < 64; off <<= 1) {
            const unsigned long long ok = __shfl_xor(best, off);
            best = ok < best ? ok : best;
        }
        if ((tid & 63) == 0) atomicMin(&skey, best);
        __syncthreads();
        if (tid == 0) widx[row] = (int)(skey & (KCODES - 1));
        __syncthreads();
    }
}

__global__ void vq_gather(const float* __restrict__ E, const int* __restrict__ widx,
                          float* __restrict__ out)
{
    const int gid = blockIdx.x * 256 + threadIdx.x;
    const int n  = gid >> 6;
    const int d4 = gid & 63;
    const int k = widx[n] & (KCODES - 1);   // safety clamp
    reinterpret_cast<float4*>(out)[(size_t)n * 64 + d4] =
        reinterpret_cast<const float4*>(E)[(size_t)k * 64 + d4];
}

extern "C" void kernel_launch(void* const* d_in, const int* in_sizes, int n_in,
                              void* d_out, int out_size, void* d_ws, size_t ws_size,
                              hipStream_t stream)
{
    const float* zp = (const float*)d_in[0];
    const float* Ep = (const float*)d_in[1];
    float* out = (float*)d_out;
    char* ws = (char*)d_ws;

    float* A32    = (float*)ws;                              // 131072 B
    float* C32    = (float*)(ws + 131072);                   //  32768 B
    int*   widx   = (int*)(ws + 163840);                     // 131072 B
    int*   counts = (int*)(ws + 294912);                     // 131072 B
    int*   badcnt = (int*)(ws + 425984);                     //     16 B
    int*   badlist = (int*)(ws + 426000);                    // 131072 B
    unsigned short* candg = (unsigned short*)(ws + 557072);  // 1 MB

    hipMemsetAsync(badcnt, 0, 4, stream);
    vq_rowsq<<<NROWS / 256, 256, 0, stream>>>(zp, A32, NROWS);
    vq_rowsq<<<KCODES / 256, 256, 0, stream>>>(Ep, C32, KCODES);
    vq_p1<<<NROWS / BM, 512, 0, stream>>>(zp, Ep, A32, C32, counts, candg, badcnt, badlist);
    vq_p2<<<NROWS / 4, 256, 0, stream>>>(zp, Ep, A32, C32, counts, candg, widx);
    vq_pfull<<<512, 1024, 0, stream>>>(zp, Ep, A32, C32, badcnt, badlist, widx);
    vq_gather<<<NROWS * (DIM / 4) / 256, 256, 0, stream>>>(Ep, widx, out);
}